// Round 9
// baseline (85.381 us; speedup 1.0000x reference)
//
#include <hip/hip_runtime.h>

#define Hdim 128
#define Wdim 128
#define Cdim 64
#define HW   (Hdim * Wdim)
#define NPIX (4 * HW)     // 65536
#define NBLK (NPIX / 64)  // 1024 blocks, 64 pixels each
#define NXCD 8
#define Hp 130            // padded dims
#define HWp (Hp * Hp)     // 16900

// XCD-aware bijective swizzle (nwg % 8 == 0): consecutive logical blocks
// (which share image rows -> x reuse) land on the SAME XCD's L2.
__device__ __forceinline__ int xcd_swizzle(int bid) {
    return (bid % NXCD) * (NBLK / NXCD) + bid / NXCD;
}

// ---------------------------------------------------------------------------
// Kernel A: fused {NCHW->padded-NHWC transpose} + {offset conv dw3x3 + pw
// 64->18} + {sampling geometry}.  (unchanged from R8)
// ---------------------------------------------------------------------------
__global__ __launch_bounds__(512) void offset_geo_kernel(
    const float* __restrict__ x,     // (B, C, H, W)
    const float* __restrict__ p_dw,  // (C, 1, 3, 3)
    const float* __restrict__ p_pw,  // (18, C, 1, 1)
    float* __restrict__ xt,          // (B, 130, 130, C) padded NHWC
    float4* __restrict__ geoW,       // (NBLK, 9, 64) bilinear weights
    int4* __restrict__ geoI)         // (NBLK, 9, 64) padded-grid corner idx
{
    __shared__ float part[8][18][64];   // 36.8 KB; part[0] reused as sum

    int lane = threadIdx.x & 63;
    int g    = threadIdx.x >> 6;
    int blk  = xcd_swizzle(blockIdx.x);
    int pix0 = blk * 64;
    int pix  = pix0 + lane;
    int w = pix & (Wdim - 1);
    int h = (pix >> 7) & (Hdim - 1);
    int b = pix >> 14;

    // --- zero the pad ring of xt (2064 ring positions x 16 float4) -------
    {
        int gid = blockIdx.x * 512 + threadIdx.x;   // raw id: blocks 0..64
        if (gid < 2064 * 16) {
            int rp  = gid >> 4, sub = gid & 15;
            int img = rp / 516, pos = rp - img * 516;
            int i, j;
            if (pos < 130)      { i = 0;   j = pos; }
            else if (pos < 260) { i = 129; j = pos - 130; }
            else { int p2 = pos - 260; i = 1 + (p2 >> 1); j = (p2 & 1) ? 129 : 0; }
            float4* dst = (float4*)(xt + ((size_t)img * HWp + i * Hp + j) * Cdim);
            dst[sub] = make_float4(0.f, 0.f, 0.f, 0.f);
        }
    }

    // --- depthwise 3x3: masks/offsets hoisted out of the channel loop ----
    int   off9[9];
    float msk9[9];
#pragma unroll
    for (int dh = -1; dh <= 1; ++dh) {
#pragma unroll
        for (int dw = -1; dw <= 1; ++dw) {
            int tap = (dh + 1) * 3 + (dw + 1);
            int hh = h + dh, ww = w + dw;
            bool ok = (hh >= 0) & (hh < Hdim) & (ww >= 0) & (ww < Wdim);
            off9[tap] = ok ? hh * Wdim + ww : 0;
            msk9[tap] = ok ? 1.f : 0.f;
        }
    }

    float t[8], ctr[8];
#pragma unroll
    for (int i = 0; i < 8; ++i) {
        int c = g * 8 + i;              // wave-uniform
        const float* xb = x + (size_t)(b * Cdim + c) * HW;
        float s = 0.f;
#pragma unroll
        for (int tap = 0; tap < 9; ++tap) {
            float v = xb[off9[tap]] * msk9[tap];
            s += v * p_dw[c * 9 + tap];
        }
        t[i]   = s;
        ctr[i] = xb[h * Wdim + w];      // transpose source (center tap)
    }

    // --- transpose write: 8 contiguous floats per thread (32B chunks) ----
    {
        size_t ppos = ((size_t)b * HWp + (h + 1) * Hp + (w + 1)) * Cdim + g * 8;
        float4* cd = (float4*)(xt + ppos);
        cd[0] = make_float4(ctr[0], ctr[1], ctr[2], ctr[3]);
        cd[1] = make_float4(ctr[4], ctr[5], ctr[6], ctr[7]);
    }

    // --- pointwise 64->18 partials -> LDS ---------------------------------
#pragma unroll
    for (int j = 0; j < 18; ++j) {
        float s = 0.f;
#pragma unroll
        for (int i = 0; i < 8; ++i)
            s += p_pw[j * Cdim + g * 8 + i] * t[i];
        part[g][j][lane] = s;
    }
    __syncthreads();

    // reduce 8 partials into part[0]
#pragma unroll
    for (int it = 0; it < 3; ++it) {
        int idx = threadIdx.x + it * 512;
        if (idx < 18 * 64) {
            int j = idx >> 6;
            int p = idx & 63;
            float s = part[0][j][p];
#pragma unroll
            for (int q = 1; q < 8; ++q) s += part[q][j][p];
            part[0][j][p] = s;
        }
    }
    __syncthreads();

    // --- geometry pass: reference formulas verbatim on the padded grid ---
#pragma unroll
    for (int it = 0; it < 2; ++it) {
        int idx = threadIdx.x + it * 512;
        if (idx < 9 * 64) {
            int k = idx >> 6;
            int p = idx & 63;
            int ppix = pix0 + p;
            int pw2 = ppix & (Wdim - 1);
            int ph2 = (ppix >> 7) & (Hdim - 1);

            float px = (float)(ph2 + 1) + (float)(k / 3 - 1) + part[0][k][p];
            float py = (float)(pw2 + 1) + (float)(k % 3 - 1) + part[0][k + 9][p];

            float fx = floorf(px), fy = floorf(py);
            float ltx = fminf(fmaxf(fx, 0.f), 129.f);
            float lty = fminf(fmaxf(fy, 0.f), 129.f);
            float rbx = fminf(fmaxf(fx + 1.f, 0.f), 129.f);
            float rby = fminf(fmaxf(fy + 1.f, 0.f), 129.f);
            float pxc = fminf(fmaxf(px, 0.f), 129.f);
            float pyc = fminf(fmaxf(py, 0.f), 129.f);

            float glt = (1.f + ltx - pxc) * (1.f + lty - pyc);
            float grb = (1.f - rbx + pxc) * (1.f - rby + pyc);
            float glb = (1.f + ltx - pxc) * (1.f - rby + pyc);
            float grt = (1.f - rbx + pxc) * (1.f + lty - pyc);

            int ix0 = (int)ltx, iy0 = (int)lty, ix1 = (int)rbx, iy1 = (int)rby;

            size_t gidx = ((size_t)blk * 9 + k) * 64 + p;
            geoW[gidx] = make_float4(glt, grb, glb, grt);
            geoI[gidx] = make_int4(ix0 * Hp + iy0,   // lt
                                   ix1 * Hp + iy1,   // rb
                                   ix0 * Hp + iy1,   // lb
                                   ix1 * Hp + iy0);  // rt
        }
    }
}

// ---------------------------------------------------------------------------
// Kernel B: deformable sampling + collapsed depthwise + pointwise.
// Phase A (restructured): two 32-lane HALVES. Lane <half, c2> owns channel
//   pair (2c2, 2c2+1) of pixel gu*8 + 2i + half.  Geometry is a per-lane
//   global_load_dwordx4 (pipelined by vmcnt, no SGPR-serialized s_loads —
//   R8 reloaded geo per-i with ~200cy SMEM latency exposed), and each corner
//   gather is a float2 load: gather instr count halves (288 -> 144/wave),
//   identical cache-line traffic.
// Phase B: lane = pixel; 64->64 pointwise, coalesced NCHW writes.
// ---------------------------------------------------------------------------
__global__ __launch_bounds__(512) void deform_kernel(
    const float* __restrict__ xt,    // (B, 130, 130, C) padded NHWC
    const float* __restrict__ c_dw,  // (C, 1, 3, 3)
    const float* __restrict__ c_pw,  // (C, C, 1, 1)
    const float4* __restrict__ geoW, // (NBLK, 9, 64)
    const int4* __restrict__ geoI,   // (NBLK, 9, 64)
    float* __restrict__ out)         // (B, C, H, W)
{
    __shared__ float  accs[64][66];  // [pixel][channel], stride 66 (2-way max)
    __shared__ float2 cdwT2[9][32];  // c_dw transposed, channel-paired

    int lane = threadIdx.x & 63;
    int half = lane >> 5;            // which 32-lane half
    int c2   = lane & 31;            // channel pair index -> ch 2c2, 2c2+1
    int gu   = __builtin_amdgcn_readfirstlane(threadIdx.x >> 6);
    int blk  = xcd_swizzle(blockIdx.x);
    int pix0 = blk * 64;
    int b    = pix0 >> 14;           // block-uniform
    const float* xb = xt + (size_t)b * HWp * Cdim;

    // stage c_dw as channel-paired transpose: cdwT2[k][c2] = (c_dw[2c2*9+k], c_dw[(2c2+1)*9+k])
    for (int idx = threadIdx.x; idx < 9 * 32; idx += 512) {
        int k = idx >> 5, cc = idx & 31;
        cdwT2[k][cc] = make_float2(c_dw[(2 * cc) * 9 + k], c_dw[(2 * cc + 1) * 9 + k]);
    }
    __syncthreads();

    // Phase A
    float2 acc2[4];
#pragma unroll
    for (int i = 0; i < 4; ++i) acc2[i] = make_float2(0.f, 0.f);

    for (int k = 0; k < 9; ++k) {
        float2 wk2 = cdwT2[k][c2];
        const float4* gW = geoW + ((size_t)blk * 9 + k) * 64 + gu * 8;
        const int4*   gI = geoI + ((size_t)blk * 9 + k) * 64 + gu * 8;
#pragma unroll
        for (int i = 0; i < 4; ++i) {
            float4 wv = gW[2 * i + half];   // per-lane (uniform per half)
            int4   iv = gI[2 * i + half];
            float2 vlt = *(const float2*)(xb + (size_t)iv.x * Cdim + 2 * c2);
            float2 vrb = *(const float2*)(xb + (size_t)iv.y * Cdim + 2 * c2);
            float2 vlb = *(const float2*)(xb + (size_t)iv.z * Cdim + 2 * c2);
            float2 vrt = *(const float2*)(xb + (size_t)iv.w * Cdim + 2 * c2);
            float sx = wv.x * vlt.x + wv.y * vrb.x + wv.z * vlb.x + wv.w * vrt.x;
            float sy = wv.x * vlt.y + wv.y * vrb.y + wv.z * vlb.y + wv.w * vrt.y;
            acc2[i].x += wk2.x * sx;
            acc2[i].y += wk2.y * sy;
        }
    }

#pragma unroll
    for (int i = 0; i < 4; ++i)
        *(float2*)&accs[gu * 8 + 2 * i + half][2 * c2] = acc2[i];
    __syncthreads();

    // Phase B: lane = pixel; 64->64 pointwise, wave-uniform weights.
    int pix = pix0 + lane;
    int hw  = pix & (HW - 1);

    float s[8];
#pragma unroll
    for (int i = 0; i < 8; ++i) s[i] = 0.f;

    for (int c0 = 0; c0 < Cdim; c0 += 8) {
        float xc[8];
#pragma unroll
        for (int q = 0; q < 8; ++q) xc[q] = accs[lane][c0 + q];
#pragma unroll
        for (int i = 0; i < 8; ++i) {
#pragma unroll
            for (int q = 0; q < 8; ++q)
                s[i] += c_pw[(gu * 8 + i) * Cdim + c0 + q] * xc[q];
        }
    }

    size_t obase = (size_t)b * Cdim * HW + hw;
#pragma unroll
    for (int i = 0; i < 8; ++i)
        out[obase + (size_t)(gu * 8 + i) * HW] = s[i];
}

extern "C" void kernel_launch(void* const* d_in, const int* in_sizes, int n_in,
                              void* d_out, int out_size, void* d_ws, size_t ws_size,
                              hipStream_t stream) {
    const float* x    = (const float*)d_in[0];
    const float* p_dw = (const float*)d_in[1];
    const float* p_pw = (const float*)d_in[2];
    const float* c_dw = (const float*)d_in[3];
    const float* c_pw = (const float*)d_in[4];
    float* out = (float*)d_out;

    float*  xt   = (float*)d_ws;                                   // 17.3 MB padded NHWC
    float4* geoW = (float4*)((char*)d_ws + (size_t)4 * HWp * Cdim * 4);
    int4*   geoI = (int4*)((char*)geoW + (size_t)NBLK * 9 * 64 * sizeof(float4));

    dim3 blk(512);
    dim3 grd(NBLK);
    offset_geo_kernel<<<grd, blk, 0, stream>>>(x, p_dw, p_pw, xt, geoW, geoI);
    deform_kernel<<<grd, blk, 0, stream>>>(xt, c_dw, c_pw, geoW, geoI, out);
}

// Round 10
// 65.730 us; speedup vs baseline: 1.2990x; 1.2990x over previous
//
#include <hip/hip_runtime.h>

#define Hdim 128
#define Wdim 128
#define Cdim 64
#define HW   (Hdim * Wdim)
#define NPIX (4 * HW)     // 65536
#define NBLK (NPIX / 64)  // 1024 blocks, 64 pixels each
#define NXCD 8
#define Hp 130            // padded dims
#define HWp (Hp * Hp)     // 16900

// XCD-aware bijective swizzle (nwg % 8 == 0): consecutive logical blocks
// (which share image rows -> x reuse) land on the SAME XCD's L2.
__device__ __forceinline__ int xcd_swizzle(int bid) {
    return (bid % NXCD) * (NBLK / NXCD) + bid / NXCD;
}

// geo layout: [blk][g:8 waves][k:9][i:8 px][8 dwords {w0..w3, i0..i3}]
// -> one wave's geometry = 576 contiguous dwords (2304 B).

// ---------------------------------------------------------------------------
// Kernel A: fused {NCHW->padded-NHWC transpose} + {offset conv dw3x3 + pw
// 64->18} + {sampling geometry}.  (R8 structure; only geo layout changed)
// ---------------------------------------------------------------------------
__global__ __launch_bounds__(512) void offset_geo_kernel(
    const float* __restrict__ x,     // (B, C, H, W)
    const float* __restrict__ p_dw,  // (C, 1, 3, 3)
    const float* __restrict__ p_pw,  // (18, C, 1, 1)
    float* __restrict__ xt,          // (B, 130, 130, C) padded NHWC
    float* __restrict__ geo)         // (NBLK, 8, 9, 8, 8) dwords
{
    __shared__ float part[8][18][64];   // 36.8 KB; part[0] reused as sum

    int lane = threadIdx.x & 63;
    int g    = threadIdx.x >> 6;
    int blk  = xcd_swizzle(blockIdx.x);
    int pix0 = blk * 64;
    int pix  = pix0 + lane;
    int w = pix & (Wdim - 1);
    int h = (pix >> 7) & (Hdim - 1);
    int b = pix >> 14;

    // --- zero the pad ring of xt (2064 ring positions x 16 float4) -------
    {
        int gid = blockIdx.x * 512 + threadIdx.x;   // raw id: blocks 0..64
        if (gid < 2064 * 16) {
            int rp  = gid >> 4, sub = gid & 15;
            int img = rp / 516, pos = rp - img * 516;
            int i, j;
            if (pos < 130)      { i = 0;   j = pos; }
            else if (pos < 260) { i = 129; j = pos - 130; }
            else { int p2 = pos - 260; i = 1 + (p2 >> 1); j = (p2 & 1) ? 129 : 0; }
            float4* dst = (float4*)(xt + ((size_t)img * HWp + i * Hp + j) * Cdim);
            dst[sub] = make_float4(0.f, 0.f, 0.f, 0.f);
        }
    }

    // --- depthwise 3x3: masks/offsets hoisted out of the channel loop ----
    int   off9[9];
    float msk9[9];
#pragma unroll
    for (int dh = -1; dh <= 1; ++dh) {
#pragma unroll
        for (int dw = -1; dw <= 1; ++dw) {
            int tap = (dh + 1) * 3 + (dw + 1);
            int hh = h + dh, ww = w + dw;
            bool ok = (hh >= 0) & (hh < Hdim) & (ww >= 0) & (ww < Wdim);
            off9[tap] = ok ? hh * Wdim + ww : 0;
            msk9[tap] = ok ? 1.f : 0.f;
        }
    }

    float t[8], ctr[8];
#pragma unroll
    for (int i = 0; i < 8; ++i) {
        int c = g * 8 + i;              // wave-uniform
        const float* xb = x + (size_t)(b * Cdim + c) * HW;
        float s = 0.f;
#pragma unroll
        for (int tap = 0; tap < 9; ++tap) {
            float v = xb[off9[tap]] * msk9[tap];
            s += v * p_dw[c * 9 + tap];
        }
        t[i]   = s;
        ctr[i] = xb[h * Wdim + w];      // transpose source (center tap)
    }

    // --- transpose write: 8 contiguous floats per thread (32B chunks) ----
    {
        size_t ppos = ((size_t)b * HWp + (h + 1) * Hp + (w + 1)) * Cdim + g * 8;
        float4* cd = (float4*)(xt + ppos);
        cd[0] = make_float4(ctr[0], ctr[1], ctr[2], ctr[3]);
        cd[1] = make_float4(ctr[4], ctr[5], ctr[6], ctr[7]);
    }

    // --- pointwise 64->18 partials -> LDS ---------------------------------
#pragma unroll
    for (int j = 0; j < 18; ++j) {
        float s = 0.f;
#pragma unroll
        for (int i = 0; i < 8; ++i)
            s += p_pw[j * Cdim + g * 8 + i] * t[i];
        part[g][j][lane] = s;
    }
    __syncthreads();

    // reduce 8 partials into part[0]
#pragma unroll
    for (int it = 0; it < 3; ++it) {
        int idx = threadIdx.x + it * 512;
        if (idx < 18 * 64) {
            int j = idx >> 6;
            int p = idx & 63;
            float s = part[0][j][p];
#pragma unroll
            for (int q = 1; q < 8; ++q) s += part[q][j][p];
            part[0][j][p] = s;
        }
    }
    __syncthreads();

    // --- geometry pass: reference formulas verbatim on the padded grid ---
#pragma unroll
    for (int it = 0; it < 2; ++it) {
        int idx = threadIdx.x + it * 512;
        if (idx < 9 * 64) {
            int k = idx >> 6;
            int p = idx & 63;
            int ppix = pix0 + p;
            int pw2 = ppix & (Wdim - 1);
            int ph2 = (ppix >> 7) & (Hdim - 1);

            float px = (float)(ph2 + 1) + (float)(k / 3 - 1) + part[0][k][p];
            float py = (float)(pw2 + 1) + (float)(k % 3 - 1) + part[0][k + 9][p];

            float fx = floorf(px), fy = floorf(py);
            float ltx = fminf(fmaxf(fx, 0.f), 129.f);
            float lty = fminf(fmaxf(fy, 0.f), 129.f);
            float rbx = fminf(fmaxf(fx + 1.f, 0.f), 129.f);
            float rby = fminf(fmaxf(fy + 1.f, 0.f), 129.f);
            float pxc = fminf(fmaxf(px, 0.f), 129.f);
            float pyc = fminf(fmaxf(py, 0.f), 129.f);

            float glt = (1.f + ltx - pxc) * (1.f + lty - pyc);
            float grb = (1.f - rbx + pxc) * (1.f - rby + pyc);
            float glb = (1.f + ltx - pxc) * (1.f - rby + pyc);
            float grt = (1.f - rbx + pxc) * (1.f + lty - pyc);

            int ix0 = (int)ltx, iy0 = (int)lty, ix1 = (int)rbx, iy1 = (int)rby;

            // entry = ((blk*8 + g)*9 + k)*8 + i   (g = p>>3, i = p&7)
            size_t e = (((size_t)blk * 8 + (p >> 3)) * 9 + k) * 8 + (p & 7);
            float4* wdst = (float4*)(geo + e * 8);
            int4*   idst = (int4*)(geo + e * 8 + 4);
            *wdst = make_float4(glt, grb, glb, grt);
            *idst = make_int4(ix0 * Hp + iy0,   // lt
                              ix1 * Hp + iy1,   // rb
                              ix0 * Hp + iy1,   // lb
                              ix1 * Hp + iy0);  // rt
        }
    }
}

// ---------------------------------------------------------------------------
// Kernel B: deformable sampling + collapsed depthwise + pointwise.
// Phase A: lane = channel.  The wave's ENTIRE geometry (72 entries x 32B)
//   is prefetched ONCE with 9 coalesced per-lane dword loads, then broadcast
//   per (k,i) via compile-time v_readlane -> SGPRs.  No memory latency in
//   the hot loop; gathers keep the fast saddr form (SGPR base + lane*4).
//   (R8 issued 144 serialized s_loads that missed L2 -> ~44us; R9's per-lane
//   geo loads broke saddr gathers -> 62us.)
// Phase B: lane = pixel; 64->64 pointwise, coalesced NCHW writes.
// ---------------------------------------------------------------------------
__global__ __launch_bounds__(512) void deform_kernel(
    const float* __restrict__ xt,    // (B, 130, 130, C) padded NHWC
    const float* __restrict__ c_dw,  // (C, 1, 3, 3)
    const float* __restrict__ c_pw,  // (C, C, 1, 1)
    const int* __restrict__ geo,     // (NBLK, 8, 9, 8, 8) dwords
    float* __restrict__ out)         // (B, C, H, W)
{
    __shared__ float accs[64][65];   // [pixel][channel] padded, 16.6 KB

    int lane = threadIdx.x & 63;
    int gu   = __builtin_amdgcn_readfirstlane(threadIdx.x >> 6);
    int blk  = xcd_swizzle(blockIdx.x);
    int pix0 = blk * 64;
    int b    = pix0 >> 14;           // block-uniform
    const float* xb = xt + (size_t)b * HWp * Cdim;

    // prefetch this wave's geometry: 576 dwords -> 9 VGPRs per lane
    int gv0, gv1, gv2, gv3, gv4, gv5, gv6, gv7, gv8;
    {
        const int* gb = geo + ((size_t)blk * 8 + gu) * 576 + lane;
        gv0 = gb[0];   gv1 = gb[64];  gv2 = gb[128];
        gv3 = gb[192]; gv4 = gb[256]; gv5 = gb[320];
        gv6 = gb[384]; gv7 = gb[448]; gv8 = gb[512];
    }
    // per-lane depthwise weights (lane = channel)
    float wk9[9];
#pragma unroll
    for (int k = 0; k < 9; ++k) wk9[k] = c_dw[lane * 9 + k];

#define GV(r) ((r)==0?gv0:(r)==1?gv1:(r)==2?gv2:(r)==3?gv3:(r)==4?gv4: \
               (r)==5?gv5:(r)==6?gv6:(r)==7?gv7:gv8)
#define RL(f) __builtin_amdgcn_readlane(GV((f) >> 6), (f) & 63)

    float acc[8];
#pragma unroll
    for (int i = 0; i < 8; ++i) acc[i] = 0.f;

#pragma unroll
    for (int k = 0; k < 9; ++k) {
#pragma unroll
        for (int i = 0; i < 8; ++i) {
            const int f = (k * 8 + i) * 8;
            float glt = __int_as_float(RL(f + 0));
            float grb = __int_as_float(RL(f + 1));
            float glb = __int_as_float(RL(f + 2));
            float grt = __int_as_float(RL(f + 3));
            const float* plt = xb + (size_t)RL(f + 4) * Cdim;
            const float* prb = xb + (size_t)RL(f + 5) * Cdim;
            const float* plb = xb + (size_t)RL(f + 6) * Cdim;
            const float* prt = xb + (size_t)RL(f + 7) * Cdim;
            float sv = glt * plt[lane] + grb * prb[lane]
                     + glb * plb[lane] + grt * prt[lane];
            acc[i] += wk9[k] * sv;
        }
    }
#undef RL
#undef GV

#pragma unroll
    for (int i = 0; i < 8; ++i) accs[gu * 8 + i][lane] = acc[i];
    __syncthreads();

    // Phase B: lane = pixel; 64->64 pointwise, wave-uniform weights.
    int pix = pix0 + lane;
    int hw  = pix & (HW - 1);

    float s[8];
#pragma unroll
    for (int i = 0; i < 8; ++i) s[i] = 0.f;

    for (int c0 = 0; c0 < Cdim; c0 += 8) {
        float xc[8];
#pragma unroll
        for (int q = 0; q < 8; ++q) xc[q] = accs[lane][c0 + q];
#pragma unroll
        for (int i = 0; i < 8; ++i) {
#pragma unroll
            for (int q = 0; q < 8; ++q)
                s[i] += c_pw[(gu * 8 + i) * Cdim + c0 + q] * xc[q];
        }
    }

    size_t obase = (size_t)b * Cdim * HW + hw;
#pragma unroll
    for (int i = 0; i < 8; ++i)
        out[obase + (size_t)(gu * 8 + i) * HW] = s[i];
}

extern "C" void kernel_launch(void* const* d_in, const int* in_sizes, int n_in,
                              void* d_out, int out_size, void* d_ws, size_t ws_size,
                              hipStream_t stream) {
    const float* x    = (const float*)d_in[0];
    const float* p_dw = (const float*)d_in[1];
    const float* p_pw = (const float*)d_in[2];
    const float* c_dw = (const float*)d_in[3];
    const float* c_pw = (const float*)d_in[4];
    float* out = (float*)d_out;

    float* xt  = (float*)d_ws;                                  // 17.3 MB padded NHWC
    float* geo = (float*)((char*)d_ws + (size_t)4 * HWp * Cdim * 4);  // 18.9 MB

    dim3 blk(512);
    dim3 grd(NBLK);
    offset_geo_kernel<<<grd, blk, 0, stream>>>(x, p_dw, p_pw, xt, geo);
    deform_kernel<<<grd, blk, 0, stream>>>(xt, c_dw, c_pw, (const int*)geo, out);
}